// Round 7
// baseline (394.274 us; speedup 1.0000x reference)
//
#include <hip/hip_runtime.h>
#include <stdint.h>

#define N_NODES 100000
#define N_EDGES 1600000
#define NBLK_SCAN 391   // ceil(N_NODES/256)

typedef __attribute__((ext_vector_type(8))) short short8;
typedef __attribute__((ext_vector_type(4))) float float4v;

__device__ __forceinline__ unsigned short f32_to_bf16(float f) {
  uint32_t u = __float_as_uint(f);
  u += 0x7fffu + ((u >> 16) & 1u);   // RNE
  return (unsigned short)(u >> 16);
}
__device__ __forceinline__ float bf16_to_f32(unsigned short h) {
  return __uint_as_float(((uint32_t)h) << 16);
}

// ---------------------------------------------------------------------------
// K_zero: deg=0; build wbf = 54 MFMA A-fragment tiles (TRANSPOSED scheme:
// A = W^T so D rows = features, D cols = nodes):
//   tiles 0..49 : A[row=fo_local][k=fin] = weight[km=t>>1][fin][(t&1)*16+row]
//   tiles 50,51 : root_w^T
//   tiles 52,53 : wvec[km][fin] = sum_fo weight[km][fin][fo]*att_w[32+fo]
// slot((t,q,row,j)) = t*512 + q*128 + row*8 + j,  fin = q*8+j.
// Also zero the xw pad row.
// ---------------------------------------------------------------------------
__global__ __launch_bounds__(256) void k_zero(
    const float* __restrict__ weight, const float* __restrict__ root_w,
    const float* __restrict__ att_w,
    int* __restrict__ deg, unsigned short* __restrict__ wbf,
    unsigned short* __restrict__ xw) {
  int tid = threadIdx.x;
  int b = blockIdx.x;
  int i = b * 256 + tid;
  if (i < N_NODES) deg[i] = 0;
  if (b < 100) {            // 25600 weight-tile slots
    int e = i;
    int t = e >> 9, rem = e & 511;
    int q = rem >> 7, row = (rem >> 3) & 15, j = rem & 7;
    int km = t >> 1, fin = q * 8 + j, fo = (t & 1) * 16 + row;
    wbf[e] = f32_to_bf16(weight[(km * 32 + fin) * 32 + fo]);
  } else if (b == 100) {
    // root tiles 50,51
    for (int idx = tid; idx < 1024; idx += 256) {
      int t = 50 + (idx >> 9), rem = idx & 511;
      int q = rem >> 7, row = (rem >> 3) & 15, j = rem & 7;
      int fin = q * 8 + j, fo = (t - 50) * 16 + row;
      wbf[t * 512 + rem] = f32_to_bf16(root_w[fin * 32 + fo]);
    }
    // wvec tiles 52,53 (ydot weights)
    for (int idx = tid; idx < 1024; idx += 256) {
      int t = 52 + (idx >> 9), rem = idx & 511;
      int q = rem >> 7, row = (rem >> 3) & 15, j = rem & 7;
      int fin = q * 8 + j, km = (t - 52) * 16 + row;
      float s = 0.f;
      if (km < 25) {
#pragma unroll
        for (int fo = 0; fo < 32; fo++)
          s += weight[(km * 32 + fin) * 32 + fo] * att_w[32 + fo];
      }
      wbf[t * 512 + rem] = f32_to_bf16(s);
    }
  } else if (b == 101) {    // xw pad row (node 100000), 1600 B
    if (tid < 400) ((unsigned int*)(xw + 80000000))[tid] = 0u;
  }
}

// ---------------------------------------------------------------------------
// K1a: histogram + rank ONLY (split out of k1 to isolate the 1.6M
// device-scope atomics from the MFMA/store kernel — two different k1
// implementations both pinned at 107us with nothing saturated; this split
// lets rocprof price the atomics and the writes separately).
// ---------------------------------------------------------------------------
__global__ __launch_bounds__(256) void k1a_hist(
    const int* __restrict__ ei, int* __restrict__ deg,
    unsigned short* __restrict__ rank) {
  int e = blockIdx.x * 256 + threadIdx.x;
  int r = ei[e];
  rank[e] = (unsigned short)atomicAdd(&deg[r], 1);
}

// ---------------------------------------------------------------------------
// K1b (6250 blocks, 16 nodes each) — transposed MFMA, NO atomics:
//  - D[fo][node]: lane packs 4 consecutive features of one node as uint2,
//    staged in LDS at swizzled slot tq*16 + (node ^ (tq&15)); copy-out is
//    25.6 KB of linear global per block (512 B per wave-instr).
//  - tiles 50,51 (wave 3, in-loop): out = x_root + bias; r_dot -> od[].y
//  - tiles 52,53 (peeled, waves 0,1): ydot values -> small LDS [16][33],
//    then ydq packed bf16x4 per (node,cell) DIRECTLY (k_ydq kernel fused
//    away: saves its 25.6 MB round-trip + a launch).
// ---------------------------------------------------------------------------
__global__ __launch_bounds__(256) void k1b_xw(
    const float* __restrict__ x, const unsigned short* __restrict__ wbf,
    const float* __restrict__ att_w, const float* __restrict__ bias,
    unsigned short* __restrict__ xw, float* __restrict__ out,
    uint2* __restrict__ od, uint2* __restrict__ ydq) {
  __shared__ __align__(16) uint2 st[3200];   // 25.6 KB: tiles 0..49
  __shared__ float ydl[16][33];              // 2.1 KB: ydot exchange
  int tid = threadIdx.x;
  int b = blockIdx.x;

  int wave = tid >> 6, lane = tid & 63;
  int quad = lane >> 4, c16 = lane & 15;
  int n0 = b * 16;
  int node = n0 + c16;
  // B-fragment = x^T: lane holds x[node=c16][fin = quad*8 + j]
  const float* xp = x + (size_t)node * 32 + quad * 8;
  float4 a0 = *reinterpret_cast<const float4*>(xp);
  float4 a1 = *reinterpret_cast<const float4*>(xp + 4);
  short8 af;
  af[0] = (short)f32_to_bf16(a0.x); af[1] = (short)f32_to_bf16(a0.y);
  af[2] = (short)f32_to_bf16(a0.z); af[3] = (short)f32_to_bf16(a0.w);
  af[4] = (short)f32_to_bf16(a1.x); af[5] = (short)f32_to_bf16(a1.y);
  af[6] = (short)f32_to_bf16(a1.z); af[7] = (short)f32_to_bf16(a1.w);

  float rsum = 0.f;
  for (int idx = 0; idx < 13; idx++) {
    int t = wave * 13 + idx;
    // A-fragment: lane holds A[row=c16][k=quad*8+j]
    short8 bf = *reinterpret_cast<const short8*>(wbf + ((t * 4 + quad) * 16 + c16) * 8);
    float4v acc = {0.f, 0.f, 0.f, 0.f};
    acc = __builtin_amdgcn_mfma_f32_16x16x32_bf16(bf, af, acc, 0, 0, 0);
    // D: col=lane&15=node, row=quad*4+r = fo_local
    if (t < 50) {
      uint2 pk;
      pk.x = (unsigned int)f32_to_bf16(acc[0]) |
             ((unsigned int)f32_to_bf16(acc[1]) << 16);
      pk.y = (unsigned int)f32_to_bf16(acc[2]) |
             ((unsigned int)f32_to_bf16(acc[3]) << 16);
      int tq = t * 4 + quad;
      st[tq * 16 + (c16 ^ (tq & 15))] = pk;
    } else {
      int gfo = (t - 50) * 16 + quad * 4;
      float4 bi = *reinterpret_cast<const float4*>(bias + gfo);
      float4 o;
      o.x = acc[0] + bi.x; o.y = acc[1] + bi.y;
      o.z = acc[2] + bi.z; o.w = acc[3] + bi.w;
      *reinterpret_cast<float4*>(out + (size_t)node * 32 + gfo) = o;
      float4 aw = *reinterpret_cast<const float4*>(att_w + gfo);
      rsum += acc[0] * aw.x + acc[1] * aw.y + acc[2] * aw.z + acc[3] * aw.w;
    }
  }
  if (wave < 2) {   // peeled ydot tiles 52 (wave 0), 53 (wave 1) -> LDS
    int t = 52 + wave;
    short8 bf = *reinterpret_cast<const short8*>(wbf + ((t * 4 + quad) * 16 + c16) * 8);
    float4v acc = {0.f, 0.f, 0.f, 0.f};
    acc = __builtin_amdgcn_mfma_f32_16x16x32_bf16(bf, af, acc, 0, 0, 0);
    int kmb = wave * 16 + quad * 4;
#pragma unroll
    for (int r2 = 0; r2 < 4; r2++) ydl[c16][kmb + r2] = acc[r2];
  }
  if (wave == 3) {   // wave 3 owned both root tiles -> full r_dot
    rsum += __shfl_xor(rsum, 16);
    rsum += __shfl_xor(rsum, 32);
    if (lane < 16) od[node].y = __float_as_uint(rsum);
  }
  __syncthreads();
  // ydq: one (node, cell) per thread; cells i0,i1 in 0..3; km0 = i1*5+i0.
  {
    int nd = tid >> 4, cell = tid & 15;
    int i1c = cell >> 2, i0c = cell & 3;
    int km0 = i1c * 5 + i0c;
    float y0 = ydl[nd][km0], y1 = ydl[nd][km0 + 1];
    float y2 = ydl[nd][km0 + 5], y3 = ydl[nd][km0 + 6];
    uint2 pk;
    pk.x = (unsigned int)f32_to_bf16(y0) | ((unsigned int)f32_to_bf16(y1) << 16);
    pk.y = (unsigned int)f32_to_bf16(y2) | ((unsigned int)f32_to_bf16(y3) << 16);
    ydq[(size_t)n0 * 16 + tid] = pk;
  }
  // copy-out: dst is 3200 CONSECUTIVE uint2 (block writes 25.6 KB linear)
  uint2* dst = reinterpret_cast<uint2*>(xw) + (size_t)n0 * 200;
  for (int j = tid; j < 3200; j += 256) {
    int nd = j / 200;
    int tq = j - nd * 200;
    dst[j] = st[tq * 16 + (nd ^ (tq & 15))];
  }
}

// ---------------------------------------------------------------------------
// 3-kernel exclusive scan of deg -> offs.
// ---------------------------------------------------------------------------
__global__ __launch_bounds__(256) void kscan1(const int* __restrict__ deg,
                                              int* __restrict__ incl,
                                              int* __restrict__ bsum) {
  __shared__ int s[256];
  int tid = threadIdx.x;
  int i = blockIdx.x * 256 + tid;
  int v = (i < N_NODES) ? deg[i] : 0;
  s[tid] = v;
  __syncthreads();
  for (int d = 1; d < 256; d <<= 1) {
    int t = (tid >= d) ? s[tid - d] : 0;
    __syncthreads();
    s[tid] += t;
    __syncthreads();
  }
  if (i < N_NODES) incl[i] = s[tid];
  if (tid == 255) bsum[blockIdx.x] = s[255];
}

__global__ __launch_bounds__(512) void kscan2(const int* __restrict__ bsum,
                                              int* __restrict__ bbase) {
  __shared__ int s[512];
  int tid = threadIdx.x;
  int v = (tid < NBLK_SCAN) ? bsum[tid] : 0;
  s[tid] = v;
  __syncthreads();
  for (int d = 1; d < 512; d <<= 1) {
    int t = (tid >= d) ? s[tid - d] : 0;
    __syncthreads();
    s[tid] += t;
    __syncthreads();
  }
  if (tid < NBLK_SCAN) bbase[tid] = s[tid] - v;  // exclusive
}

__global__ __launch_bounds__(256) void kscan3(const int* __restrict__ deg,
                                              int* __restrict__ offs,
                                              const int* __restrict__ bbase,
                                              uint2* __restrict__ od) {
  int i = blockIdx.x * 256 + threadIdx.x;
  if (i < N_NODES) {
    int v = offs[i] - deg[i] + bbase[i >> 8];
    offs[i] = v;
    od[i].x = (unsigned int)v;   // pack exclusive offset next to r_dot bits
  }
  if (i == 0) offs[N_NODES] = N_EDGES;
}

// ---------------------------------------------------------------------------
// K_scatter: 1 edge/thread, 6250 blocks. pos = od[row].x + rank[e].
// alpha = od[row].y + bilinear(ydq[col][cell]) ; leaky-relu ; exp.
//   eidx[pos]  = col(17b) | w0(5b) | w2(5b)   (w0=i0+5*i1, w2=w0+5;
//                pseudo in [0,1) so i0,i1 <= 3 — no clamping needed)
//   ecoef[pos] = { bf16(b0*ex)|bf16(b1*ex)<<16, bf16(b2*ex)|bf16(b3*ex)<<16 }
// Sum of coefs == ex, so k2 recovers the softmax denominator for free.
// ---------------------------------------------------------------------------
__global__ __launch_bounds__(256) void kscatter(
    const int* __restrict__ ei, const float* __restrict__ pseudo,
    const uint2* __restrict__ od, const unsigned short* __restrict__ rank,
    const uint2* __restrict__ ydq,
    unsigned int* __restrict__ eidx, uint2* __restrict__ ecoef) {
  int e = blockIdx.x * 256 + threadIdx.x;
  int r = ei[e];
  int c = ei[N_EDGES + e];
  float p0 = pseudo[2 * e] * 4.f;
  float p1 = pseudo[2 * e + 1] * 4.f;
  int rk = rank[e];
  uint2 v = od[r];
  float fl0 = floorf(p0), fl1 = floorf(p1);
  float fr0 = p0 - fl0, fr1 = p1 - fl1;
  int i0 = (int)fl0, i1 = (int)fl1;
  uint2 yq = ydq[c * 16 + i1 * 4 + i0];   // one 8B sector
  float y0 = __uint_as_float(yq.x << 16);
  float y1 = __uint_as_float(yq.x & 0xffff0000u);
  float y2 = __uint_as_float(yq.y << 16);
  float y3 = __uint_as_float(yq.y & 0xffff0000u);
  float c0 = 1.f - fr0, c1 = 1.f - fr1;
  float b0 = c0 * c1, b1 = fr0 * c1, b2 = c0 * fr1, b3 = fr0 * fr1;
  float alpha = __uint_as_float(v.y) + b0 * y0 + b1 * y1 + b2 * y2 + b3 * y3;
  alpha = alpha > 0.f ? alpha : 0.2f * alpha;
  float ex = __expf(alpha);
  int pos = (int)v.x + rk;
  int w0 = i0 + 5 * i1;
  int w2 = w0 + 5;
  uint2 pk;
  pk.x = (unsigned int)f32_to_bf16(b0 * ex) |
         ((unsigned int)f32_to_bf16(b1 * ex) << 16);
  pk.y = (unsigned int)f32_to_bf16(b2 * ex) |
         ((unsigned int)f32_to_bf16(b3 * ex) << 16);
  ecoef[pos] = pk;
  eidx[pos] = (unsigned int)c | ((unsigned int)w0 << 17) |
              ((unsigned int)w2 << 22);
}

// ---------------------------------------------------------------------------
// K2: one wave per node; halves process alternate edges (lane=f_out);
// 4-deep unroll per half. Slim loop: NO shuffle reduction, NO exp —
// acc += sum_s q_s * g_s (== msg*ex), den += sum_s q_s (== ex).
// ---------------------------------------------------------------------------
__global__ __launch_bounds__(256) void k2_csr(
    const int* __restrict__ offs, const unsigned int* __restrict__ eidx,
    const uint2* __restrict__ ecoef, const unsigned short* __restrict__ xw,
    float* __restrict__ out) {
  int tid = threadIdx.x;
  int wave = tid >> 6, lane = tid & 63;
  int node = blockIdx.x * 4 + wave;
  if (node >= N_NODES) return;
  int f = lane & 31, half = lane >> 5;
  int s0 = offs[node], s1 = offs[node + 1];
  const unsigned short* xwf = xw + f;
  float accA = 0.f, accB = 0.f, denA = 0.f, denB = 0.f;
  int i = s0 + half;

  for (; i + 6 < s1; i += 8) {
    unsigned int id[4];
    uint2 cf[4];
    id[0] = eidx[i];     id[1] = eidx[i + 2];
    id[2] = eidx[i + 4]; id[3] = eidx[i + 6];
    cf[0] = ecoef[i];     cf[1] = ecoef[i + 2];
    cf[2] = ecoef[i + 4]; cf[3] = ecoef[i + 6];
    float g0[4], g1[4], g2[4], g3[4];
#pragma unroll
    for (int u = 0; u < 4; u++) {
      const unsigned short* base = xwf + (size_t)(id[u] & 0x1FFFF) * 800;
      int o0 = ((id[u] >> 17) & 31) * 32;
      int o2 = ((id[u] >> 22) & 31) * 32;
      g0[u] = bf16_to_f32(base[o0]);
      g1[u] = bf16_to_f32(base[o0 + 32]);
      g2[u] = bf16_to_f32(base[o2]);
      g3[u] = bf16_to_f32(base[o2 + 32]);
    }
#pragma unroll
    for (int u = 0; u < 4; u++) {
      float q0 = __uint_as_float(cf[u].x << 16);
      float q1 = __uint_as_float(cf[u].x & 0xffff0000u);
      float q2 = __uint_as_float(cf[u].y << 16);
      float q3 = __uint_as_float(cf[u].y & 0xffff0000u);
      float m = q0 * g0[u] + q1 * g1[u] + q2 * g2[u] + q3 * g3[u];
      float d = (q0 + q1) + (q2 + q3);
      if (u & 1) { accB += m; denB += d; } else { accA += m; denA += d; }
    }
  }
  for (; i < s1; i += 2) {
    unsigned int idv = eidx[i];
    uint2 cfv = ecoef[i];
    const unsigned short* base = xwf + (size_t)(idv & 0x1FFFF) * 800;
    int o0 = ((idv >> 17) & 31) * 32;
    int o2 = ((idv >> 22) & 31) * 32;
    float g0 = bf16_to_f32(base[o0]);
    float g1 = bf16_to_f32(base[o0 + 32]);
    float g2 = bf16_to_f32(base[o2]);
    float g3 = bf16_to_f32(base[o2 + 32]);
    float q0 = __uint_as_float(cfv.x << 16);
    float q1 = __uint_as_float(cfv.x & 0xffff0000u);
    float q2 = __uint_as_float(cfv.y << 16);
    float q3 = __uint_as_float(cfv.y & 0xffff0000u);
    accA += q0 * g0 + q1 * g1 + q2 * g2 + q3 * g3;
    denA += (q0 + q1) + (q2 + q3);
  }

  float acc = accA + accB;
  float den = denA + denB;
  acc += __shfl_xor(acc, 32);
  den += __shfl_xor(den, 32);
  if (half == 0) out[node * 32 + f] += acc / (den + 1e-16f);
}

extern "C" void kernel_launch(void* const* d_in, const int* in_sizes, int n_in,
                              void* d_out, int out_size, void* d_ws, size_t ws_size,
                              hipStream_t stream) {
  const float* x      = (const float*)d_in[0];
  const int*   ei     = (const int*)d_in[1];
  const float* pseudo = (const float*)d_in[2];
  const float* weight = (const float*)d_in[3];
  const float* root_w = (const float*)d_in[4];
  const float* att_w  = (const float*)d_in[5];
  const float* bias   = (const float*)d_in[6];
  float* out = (float*)d_out;

  char* ws = (char*)d_ws;
  unsigned short* xw   = (unsigned short*)ws;                 // 160,001,600 B (incl. 1600B pad row)
  uint2* ydq           = (uint2*)(ws + 160001600);            //  12,800,000 B
  uint2* od            = (uint2*)(ws + 172801600);            //     800,000 B {offs, r_dot bits}
  unsigned short* wbf  = (unsigned short*)(ws + 173601600);   //      55,296 B (54 tiles)
  int* deg             = (int*)(ws + 173656896);              //     400,000 B
  int* offs            = (int*)(ws + 174056896);              //     400,016 B
  int* bsum            = (int*)(ws + 174456912);              //       1,600 B
  int* bbase           = (int*)(ws + 174458512);              //       1,600 B
  unsigned short* rank = (unsigned short*)(ws + 174460112);   //   3,200,000 B
  uint2* ecoef         = (uint2*)(ws + 177660112);            //  12,800,000 B
  unsigned int* eidx   = (unsigned int*)(ws + 190460112);     //   6,400,000 B -> 196.86 MB

  hipLaunchKernelGGL(k_zero, dim3(NBLK_SCAN), dim3(256), 0, stream,
                     weight, root_w, att_w, deg, wbf, xw);
  hipLaunchKernelGGL(k1a_hist, dim3(6250), dim3(256), 0, stream, ei, deg, rank);
  hipLaunchKernelGGL(k1b_xw, dim3(6250), dim3(256), 0, stream,
                     x, wbf, att_w, bias, xw, out, od, ydq);
  hipLaunchKernelGGL(kscan1, dim3(NBLK_SCAN), dim3(256), 0, stream, deg, offs, bsum);
  hipLaunchKernelGGL(kscan2, dim3(1), dim3(512), 0, stream, bsum, bbase);
  hipLaunchKernelGGL(kscan3, dim3(NBLK_SCAN), dim3(256), 0, stream, deg, offs, bbase, od);
  hipLaunchKernelGGL(kscatter, dim3(6250), dim3(256), 0, stream,
                     ei, pseudo, od, rank, ydq, eidx, ecoef);
  hipLaunchKernelGGL(k2_csr, dim3(25000), dim3(256), 0, stream,
                     offs, eidx, ecoef, xw, out);
}

// Round 8
// 333.019 us; speedup vs baseline: 1.1839x; 1.1839x over previous
//
#include <hip/hip_runtime.h>
#include <stdint.h>

#define N_NODES 100000
#define N_EDGES 1600000
#define NBLK_SCAN 391   // ceil(N_NODES/256)

typedef __attribute__((ext_vector_type(8))) short short8;
typedef __attribute__((ext_vector_type(4))) float float4v;

__device__ __forceinline__ unsigned short f32_to_bf16(float f) {
  uint32_t u = __float_as_uint(f);
  u += 0x7fffu + ((u >> 16) & 1u);   // RNE
  return (unsigned short)(u >> 16);
}
__device__ __forceinline__ float bf16_to_f32(unsigned short h) {
  return __uint_as_float(((uint32_t)h) << 16);
}

// ---------------------------------------------------------------------------
// K_zero: deg=0; build wbf = 52 MFMA A-fragment tiles (TRANSPOSED scheme:
// A = W^T so D rows = features, D cols = nodes):
//   tiles 0..49 : A[row=fo_local][k=fin] = weight[km=t>>1][fin][(t&1)*16+row]
//   tiles 50,51 : root_w^T
// slot((t,q,row,j)) = t*512 + q*128 + row*8 + j,  fin = q*8+j.
// (ydot/wvec machinery deleted: alpha is computed in k2 via shfl reduce —
//  the kscatter ydq gather cost ~102MB of random HBM lines, round-7 PMC.)
// ---------------------------------------------------------------------------
__global__ __launch_bounds__(256) void k_zero(
    const float* __restrict__ weight, const float* __restrict__ root_w,
    int* __restrict__ deg, unsigned short* __restrict__ wbf) {
  int tid = threadIdx.x;
  int b = blockIdx.x;
  int i = b * 256 + tid;
  if (i < N_NODES) deg[i] = 0;
  if (b < 100) {            // 25600 weight-tile slots
    int e = i;
    int t = e >> 9, rem = e & 511;
    int q = rem >> 7, row = (rem >> 3) & 15, j = rem & 7;
    int km = t >> 1, fin = q * 8 + j, fo = (t & 1) * 16 + row;
    wbf[e] = f32_to_bf16(weight[(km * 32 + fin) * 32 + fo]);
  } else if (b == 100) {    // root tiles 50,51
    for (int idx = tid; idx < 1024; idx += 256) {
      int t = 50 + (idx >> 9), rem = idx & 511;
      int q = rem >> 7, row = (rem >> 3) & 15, j = rem & 7;
      int fin = q * 8 + j, fo = (t - 50) * 16 + row;
      wbf[t * 512 + rem] = f32_to_bf16(root_w[fin * 32 + fo]);
    }
  }
}

// ---------------------------------------------------------------------------
// K1 (6250 blocks, 16 nodes each) — fused hist + transposed MFMA:
//  - hist: rank[e] = atomicAdd(&deg[ei[e]],1) issued first (overlaps MFMA;
//    round-7 split showed the split costs ~12us net), stored at the end.
//  - 52 tiles = 4 waves x 13: perfectly uniform loop, no peeled section.
//  - D[fo][node]: lane packs 4 consecutive features of one node as uint2,
//    staged in LDS at swizzled slot tq*16 + (node ^ (tq&15)); copy-out is
//    25.6 KB of linear global per block (512 B per wave-instr).
//  - tiles 50,51 (wave 3, in-loop): out = x_root + bias; r_dot -> od[].y
// ---------------------------------------------------------------------------
__global__ __launch_bounds__(256) void k1_xw(
    const float* __restrict__ x, const unsigned short* __restrict__ wbf,
    const int* __restrict__ ei, const float* __restrict__ att_w,
    const float* __restrict__ bias,
    int* __restrict__ deg, unsigned short* __restrict__ rank,
    unsigned short* __restrict__ xw, float* __restrict__ out,
    uint2* __restrict__ od) {
  __shared__ __align__(16) uint2 st[3200];   // 25.6 KB: tiles 0..49
  int tid = threadIdx.x;
  int b = blockIdx.x;

  int e = b * 256 + tid;
  int rk = atomicAdd(&deg[ei[e]], 1);

  int wave = tid >> 6, lane = tid & 63;
  int quad = lane >> 4, c16 = lane & 15;
  int n0 = b * 16;
  int node = n0 + c16;
  // B-fragment = x^T: lane holds x[node=c16][fin = quad*8 + j]
  const float* xp = x + (size_t)node * 32 + quad * 8;
  float4 a0 = *reinterpret_cast<const float4*>(xp);
  float4 a1 = *reinterpret_cast<const float4*>(xp + 4);
  short8 af;
  af[0] = (short)f32_to_bf16(a0.x); af[1] = (short)f32_to_bf16(a0.y);
  af[2] = (short)f32_to_bf16(a0.z); af[3] = (short)f32_to_bf16(a0.w);
  af[4] = (short)f32_to_bf16(a1.x); af[5] = (short)f32_to_bf16(a1.y);
  af[6] = (short)f32_to_bf16(a1.z); af[7] = (short)f32_to_bf16(a1.w);

  float rsum = 0.f;
  for (int idx = 0; idx < 13; idx++) {
    int t = wave * 13 + idx;
    // A-fragment: lane holds A[row=c16][k=quad*8+j]
    short8 bf = *reinterpret_cast<const short8*>(wbf + ((t * 4 + quad) * 16 + c16) * 8);
    float4v acc = {0.f, 0.f, 0.f, 0.f};
    acc = __builtin_amdgcn_mfma_f32_16x16x32_bf16(bf, af, acc, 0, 0, 0);
    // D: col=lane&15=node, row=quad*4+r = fo_local
    if (t < 50) {
      uint2 pk;
      pk.x = (unsigned int)f32_to_bf16(acc[0]) |
             ((unsigned int)f32_to_bf16(acc[1]) << 16);
      pk.y = (unsigned int)f32_to_bf16(acc[2]) |
             ((unsigned int)f32_to_bf16(acc[3]) << 16);
      int tq = t * 4 + quad;
      st[tq * 16 + (c16 ^ (tq & 15))] = pk;
    } else {               // wave 3 only: tiles 50,51
      int gfo = (t - 50) * 16 + quad * 4;
      float4 bi = *reinterpret_cast<const float4*>(bias + gfo);
      float4 o;
      o.x = acc[0] + bi.x; o.y = acc[1] + bi.y;
      o.z = acc[2] + bi.z; o.w = acc[3] + bi.w;
      *reinterpret_cast<float4*>(out + (size_t)node * 32 + gfo) = o;
      float4 aw = *reinterpret_cast<const float4*>(att_w + gfo);
      rsum += acc[0] * aw.x + acc[1] * aw.y + acc[2] * aw.z + acc[3] * aw.w;
    }
  }
  if (wave == 3) {   // wave 3 owned both root tiles -> full r_dot
    rsum += __shfl_xor(rsum, 16);
    rsum += __shfl_xor(rsum, 32);
    if (lane < 16) od[node].y = __float_as_uint(rsum);
  }
  __syncthreads();
  // copy-out: dst is 3200 CONSECUTIVE uint2 (block writes 25.6 KB linear)
  uint2* dst = reinterpret_cast<uint2*>(xw) + (size_t)n0 * 200;
  for (int j = tid; j < 3200; j += 256) {
    int nd = j / 200;
    int tq = j - nd * 200;
    dst[j] = st[tq * 16 + (nd ^ (tq & 15))];
  }
  rank[e] = (unsigned short)rk;
}

// ---------------------------------------------------------------------------
// 3-kernel exclusive scan of deg -> offs.
// ---------------------------------------------------------------------------
__global__ __launch_bounds__(256) void kscan1(const int* __restrict__ deg,
                                              int* __restrict__ incl,
                                              int* __restrict__ bsum) {
  __shared__ int s[256];
  int tid = threadIdx.x;
  int i = blockIdx.x * 256 + tid;
  int v = (i < N_NODES) ? deg[i] : 0;
  s[tid] = v;
  __syncthreads();
  for (int d = 1; d < 256; d <<= 1) {
    int t = (tid >= d) ? s[tid - d] : 0;
    __syncthreads();
    s[tid] += t;
    __syncthreads();
  }
  if (i < N_NODES) incl[i] = s[tid];
  if (tid == 255) bsum[blockIdx.x] = s[255];
}

__global__ __launch_bounds__(512) void kscan2(const int* __restrict__ bsum,
                                              int* __restrict__ bbase) {
  __shared__ int s[512];
  int tid = threadIdx.x;
  int v = (tid < NBLK_SCAN) ? bsum[tid] : 0;
  s[tid] = v;
  __syncthreads();
  for (int d = 1; d < 512; d <<= 1) {
    int t = (tid >= d) ? s[tid - d] : 0;
    __syncthreads();
    s[tid] += t;
    __syncthreads();
  }
  if (tid < NBLK_SCAN) bbase[tid] = s[tid] - v;  // exclusive
}

__global__ __launch_bounds__(256) void kscan3(const int* __restrict__ deg,
                                              int* __restrict__ offs,
                                              const int* __restrict__ bbase,
                                              uint2* __restrict__ od) {
  int i = blockIdx.x * 256 + threadIdx.x;
  if (i < N_NODES) {
    int v = offs[i] - deg[i] + bbase[i >> 8];
    offs[i] = v;
    od[i].x = (unsigned int)v;   // pack exclusive offset next to r_dot bits
  }
  if (i == 0) {
    offs[N_NODES] = N_EDGES;
    od[N_NODES].x = (unsigned int)N_EDGES;   // k2 reads od[node+1].x
  }
}

// ---------------------------------------------------------------------------
// K_scatter: 1 edge/thread, 6250 blocks — pure pos-scatter of ONE 8B packet
// (round-7 PMC: the alpha/ydq version paid ~102MB random ydq lines + ~100MB
// scattered write churn across two arrays; this is a single 32B sector/edge).
//   epack.x = col(17b) | w0(5b) | w2(5b)   (w0=i0+5*i1, w2=w0+5)
//   epack.y = fr0_q16 | fr1_q16<<16        (16-bit fixed point, err ~8e-6)
// ---------------------------------------------------------------------------
__global__ __launch_bounds__(256) void kscatter(
    const int* __restrict__ ei, const float* __restrict__ pseudo,
    const uint2* __restrict__ od, const unsigned short* __restrict__ rank,
    uint2* __restrict__ epack) {
  int e = blockIdx.x * 256 + threadIdx.x;
  int r = ei[e];
  int c = ei[N_EDGES + e];
  float p0 = pseudo[2 * e] * 4.f;
  float p1 = pseudo[2 * e + 1] * 4.f;
  int rk = rank[e];
  unsigned int offr = od[r].x;      // one random 8B line (800KB, L2-friendly)
  float fl0 = floorf(p0), fl1 = floorf(p1);
  float fr0 = p0 - fl0, fr1 = p1 - fl1;
  int i0 = (int)fl0, i1 = (int)fl1;
  int w0 = i0 + 5 * i1;
  int w2 = w0 + 5;
  unsigned int q0 = (unsigned int)(fr0 * 65535.f + 0.5f);
  unsigned int q1 = (unsigned int)(fr1 * 65535.f + 0.5f);
  uint2 pk;
  pk.x = (unsigned int)c | ((unsigned int)w0 << 17) | ((unsigned int)w2 << 22);
  pk.y = q0 | (q1 << 16);
  epack[offr + rk] = pk;
}

// ---------------------------------------------------------------------------
// K2: one wave per node; halves process alternate edges (lane=f_out);
// 4-deep unroll per half. Computes alpha inline: msg from 4 xw gathers,
// t = msg.att2 via 5-step shfl_xor reduce (within the 32-lane half),
// leaky-relu + exp, acc += msg*ex, den += ex.
// Reads {offs, r_dot} from the packed od array (single load).
// ---------------------------------------------------------------------------
__global__ __launch_bounds__(256) void k2_csr(
    const uint2* __restrict__ od, const uint2* __restrict__ epack,
    const unsigned short* __restrict__ xw, const float* __restrict__ att_w,
    float* __restrict__ out) {
  int tid = threadIdx.x;
  int wave = tid >> 6, lane = tid & 63;
  int node = blockIdx.x * 4 + wave;
  if (node >= N_NODES) return;
  int f = lane & 31, half = lane >> 5;
  uint2 v0 = od[node];
  int s0 = (int)v0.x;
  int s1 = (int)od[node + 1].x;
  float rd = __uint_as_float(v0.y);
  float a2 = att_w[32 + f];
  const unsigned short* xwf = xw + f;
  float acc = 0.f, den = 0.f;
  int i = s0 + half;
  const float Q = 1.f / 65535.f;

  for (; i + 6 < s1; i += 8) {
    uint2 p[4];
    p[0] = epack[i];     p[1] = epack[i + 2];
    p[2] = epack[i + 4]; p[3] = epack[i + 6];
    int col[4], o0[4], o2[4];
    float fr0[4], fr1[4];
#pragma unroll
    for (int u = 0; u < 4; u++) {
      col[u] = (int)(p[u].x & 0x1FFFF);
      o0[u] = (int)((p[u].x >> 17) & 31) * 32;
      o2[u] = (int)((p[u].x >> 22) & 31) * 32;
      fr0[u] = (float)(p[u].y & 0xffff) * Q;
      fr1[u] = (float)(p[u].y >> 16) * Q;
    }
    float g0[4], g1[4], g2[4], g3[4];
#pragma unroll
    for (int u = 0; u < 4; u++) {
      const unsigned short* base = xwf + (size_t)col[u] * 800;
      g0[u] = bf16_to_f32(base[o0[u]]);
      g1[u] = bf16_to_f32(base[o0[u] + 32]);
      g2[u] = bf16_to_f32(base[o2[u]]);
      g3[u] = bf16_to_f32(base[o2[u] + 32]);
    }
    float msg[4], t[4];
#pragma unroll
    for (int u = 0; u < 4; u++) {
      float c0 = 1.f - fr0[u], c1 = 1.f - fr1[u];
      msg[u] = c1 * (c0 * g0[u] + fr0[u] * g1[u]) +
               fr1[u] * (c0 * g2[u] + fr0[u] * g3[u]);
      t[u] = msg[u] * a2;
    }
#pragma unroll
    for (int m = 16; m >= 1; m >>= 1) {
      t[0] += __shfl_xor(t[0], m);
      t[1] += __shfl_xor(t[1], m);
      t[2] += __shfl_xor(t[2], m);
      t[3] += __shfl_xor(t[3], m);
    }
#pragma unroll
    for (int u = 0; u < 4; u++) {
      float alpha = rd + t[u];
      alpha = alpha > 0.f ? alpha : 0.2f * alpha;
      float ex = __expf(alpha);
      acc += msg[u] * ex;
      den += ex;
    }
  }
  for (; i < s1; i += 2) {
    uint2 pv = epack[i];
    int col = (int)(pv.x & 0x1FFFF);
    int o0 = (int)((pv.x >> 17) & 31) * 32;
    int o2 = (int)((pv.x >> 22) & 31) * 32;
    float fr0 = (float)(pv.y & 0xffff) * Q;
    float fr1 = (float)(pv.y >> 16) * Q;
    const unsigned short* base = xwf + (size_t)col * 800;
    float g0 = bf16_to_f32(base[o0]);
    float g1 = bf16_to_f32(base[o0 + 32]);
    float g2 = bf16_to_f32(base[o2]);
    float g3 = bf16_to_f32(base[o2 + 32]);
    float c0 = 1.f - fr0, c1 = 1.f - fr1;
    float msg = c1 * (c0 * g0 + fr0 * g1) + fr1 * (c0 * g2 + fr0 * g3);
    float t = msg * a2;
#pragma unroll
    for (int m = 16; m >= 1; m >>= 1) t += __shfl_xor(t, m);
    float alpha = rd + t;
    alpha = alpha > 0.f ? alpha : 0.2f * alpha;
    float ex = __expf(alpha);
    acc += msg * ex;
    den += ex;
  }

  acc += __shfl_xor(acc, 32);
  den += __shfl_xor(den, 32);
  if (half == 0) out[node * 32 + f] += acc / (den + 1e-16f);
}

extern "C" void kernel_launch(void* const* d_in, const int* in_sizes, int n_in,
                              void* d_out, int out_size, void* d_ws, size_t ws_size,
                              hipStream_t stream) {
  const float* x      = (const float*)d_in[0];
  const int*   ei     = (const int*)d_in[1];
  const float* pseudo = (const float*)d_in[2];
  const float* weight = (const float*)d_in[3];
  const float* root_w = (const float*)d_in[4];
  const float* att_w  = (const float*)d_in[5];
  const float* bias   = (const float*)d_in[6];
  float* out = (float*)d_out;

  char* ws = (char*)d_ws;
  unsigned short* xw   = (unsigned short*)ws;                 // 160,000,000 B
  uint2* od            = (uint2*)(ws + 160000000);            //     800,016 B {offs, r_dot} x (N+1)
  unsigned short* wbf  = (unsigned short*)(ws + 160800016);   //      53,248 B (52 tiles)
  int* deg             = (int*)(ws + 160853264);              //     400,000 B
  int* offs            = (int*)(ws + 161253264);              //     400,016 B
  int* bsum            = (int*)(ws + 161653280);              //       1,600 B
  int* bbase           = (int*)(ws + 161654880);              //       1,600 B
  unsigned short* rank = (unsigned short*)(ws + 161656480);   //   3,200,000 B
  uint2* epack         = (uint2*)(ws + 164856480);            //  12,800,000 B -> 177.66 MB

  hipLaunchKernelGGL(k_zero, dim3(NBLK_SCAN), dim3(256), 0, stream,
                     weight, root_w, deg, wbf);
  hipLaunchKernelGGL(k1_xw, dim3(6250), dim3(256), 0, stream,
                     x, wbf, ei, att_w, bias, deg, rank, xw, out, od);
  hipLaunchKernelGGL(kscan1, dim3(NBLK_SCAN), dim3(256), 0, stream, deg, offs, bsum);
  hipLaunchKernelGGL(kscan2, dim3(1), dim3(512), 0, stream, bsum, bbase);
  hipLaunchKernelGGL(kscan3, dim3(NBLK_SCAN), dim3(256), 0, stream, deg, offs, bbase, od);
  hipLaunchKernelGGL(kscatter, dim3(6250), dim3(256), 0, stream,
                     ei, pseudo, od, rank, epack);
  hipLaunchKernelGGL(k2_csr, dim3(25000), dim3(256), 0, stream,
                     od, epack, xw, att_w, out);
}